// Round 4
// baseline (778.105 us; speedup 1.0000x reference)
//
#include <hip/hip_runtime.h>

// GenSP: B=4, C=64, H=W=256, st=16 -> nH=nW=16, nS=256, P=65536
// out (B,nS,P) = 256MB dense, <=9 nonzeros per pixel column.
// M_COEF=0 -> grid channels zero; f2 (pixel norm) cancels in softmax.
//
// R4: fused single kernel via hipLaunchCooperativeKernel (runtime-guaranteed
// co-residency; R3's manual-residency spin barrier timed the container out).
// Hard fallback to the exact R0 3-kernel pipeline (353.9us proven) if the
// cooperative launch is rejected. Phases (1024 blocks x 256 thr, 24.4KB LDS):
//   0: block means -> cent0; zero num/den            (== R0 k_init)
//   1: dot+softmax f32, den atomics, num via bf16 MFMA, A-frags direct from x
//   2: finalize cents, per-pixel softmax, nt-scatter 256 planes (no h-dup)
// ws float layout: num[65536] den[1024] cent0[65536] bar[2 ints]

typedef __attribute__((ext_vector_type(8))) short short8;
typedef __attribute__((ext_vector_type(4))) float f32x4;

__device__ __forceinline__ unsigned short f2bf(float f) {
  unsigned u = __float_as_uint(f);
  u += 0x7fff + ((u >> 16) & 1);   // round-nearest-even
  return (unsigned short)(u >> 16);
}

// grid barrier: valid under cooperative launch (co-residency guaranteed).
// Short bailout: if residency were ever violated, fail fast (wrong answer
// and a fast pytest failure beat a container timeout).
__device__ __forceinline__ void gridbar(int* ctr, int nblk) {
  __syncthreads();
  if (threadIdx.x == 0) {
    __threadfence();
    atomicAdd(ctr, 1);
    int spins = 0;
    while (__hip_atomic_load(ctr, __ATOMIC_ACQUIRE, __HIP_MEMORY_SCOPE_AGENT) < nblk) {
      __builtin_amdgcn_s_sleep(8);
      if (++spins > (1 << 20)) break;
    }
  }
  __syncthreads();
  __threadfence();
}

__global__ void k_zero(int* bar) {
  if (threadIdx.x < 2) bar[threadIdx.x] = 0;
}

__global__ __launch_bounds__(256, 4) void k_fused(const float* __restrict__ x,
                                                  float* __restrict__ ws,
                                                  float* __restrict__ out,
                                                  int* bar) {
  __shared__ __align__(16) char smem[24336];
  float* num = ws;
  float* den = ws + 65536;
  float* cent0 = ws + 66560;

  int t = threadIdx.x;
  int wg = blockIdx.x;

  // ================= phase 0: init (== R0 k_init) =================
  {
    float* blk = (float*)smem;   // 64 f32
    int cg = wg & 15, bi = (wg >> 4) & 15, b = wg >> 8;
    int tid = wg * 256 + t;
    if (tid < 16640) ((float4*)ws)[tid] = make_float4(0.f, 0.f, 0.f, 0.f);  // num+den
    if (t < 64) blk[t] = 0.f;
    __syncthreads();
    int sub = t >> 6, j4 = t & 63;
#pragma unroll
    for (int q = 0; q < 4; q++) {
      int c = cg * 4 + q;
      const float4* xp4 =
          (const float4*)(x + ((long)(b * 64 + c) << 16) + ((bi * 16 + sub * 4) << 8)) + j4;
      float4 a = make_float4(0.f, 0.f, 0.f, 0.f);
#pragma unroll
      for (int r = 0; r < 4; r++) {
        float4 v = xp4[r * 64];
        a.x += v.x; a.y += v.y; a.z += v.z; a.w += v.w;
      }
      float ps = a.x + a.y + a.z + a.w;
      ps += __shfl_xor(ps, 1);
      ps += __shfl_xor(ps, 2);
      if ((j4 & 3) == 0) atomicAdd(&blk[(j4 >> 2) * 4 + q], ps);
    }
    __syncthreads();
    if (t < 64) {
      int sj2 = t >> 2, q = t & 3;
      cent0[(((b << 8) + bi * 16 + sj2) << 6) + cg * 4 + q] = blk[t] * (1.f / 256.f);
    }
  }

  gridbar(bar + 0, (int)gridDim.x);

  // ================= phase 1: stat =================
  {
    unsigned short* affbf = (unsigned short*)smem;     // 16*264 u16 = 8448B
    float* cent_s = (float*)(smem + 8448);             // 9*64 f32 = 2304B
    float* c2p = (float*)(smem + 10752);               // 72 f32
    float* c2_s = (float*)(smem + 11040);              // 9 f32
    float* den_s = (float*)(smem + 11076);             // 36 f32
    int* scand = (int*)(smem + 11220);                 // 9 int

    int bj = wg & 15, bi = (wg >> 4) & 15, b = wg >> 8;

    if (t < 9) {
      int di = t / 3 - 1, dj = t % 3 - 1;
      int ci = bi + di, cj = bj + dj;
      int sc = min(max(ci, 0), 15) * 16 + min(max(cj, 0), 15);
      bool valid = ((unsigned)ci < 16u) && ((unsigned)cj < 16u);
      scand[t] = valid ? sc : (-1 - sc);
    }
    if (t < 144) {
      int k = t >> 4, f4 = t & 15;
      int di = k / 3 - 1, dj = k % 3 - 1;
      int sc = min(max(bi + di, 0), 15) * 16 + min(max(bj + dj, 0), 15);
      *(float4*)&cent_s[k * 64 + f4 * 4] =
          *(const float4*)(cent0 + (((b << 8) + sc) << 6) + f4 * 4);
    }
    __syncthreads();
    if (t < 72) {
      int k = t >> 3, pt = t & 7;
      float s = 0.f;
#pragma unroll
      for (int m = 0; m < 8; m++) { float v = cent_s[k * 64 + pt * 8 + m]; s += v * v; }
      c2p[t] = s;
    }
    __syncthreads();
    if (t < 9) {
      float s = 0.f;
#pragma unroll
      for (int m = 0; m < 8; m++) s += c2p[t * 8 + m];
      c2_s[t] = s;
    }
    __syncthreads();

    int vbits = 0;
#pragma unroll
    for (int k = 0; k < 9; k++) {
      int ci = bi + k / 3 - 1, cj = bj + k % 3 - 1;
      if ((unsigned)ci < 16u && (unsigned)cj < 16u) vbits |= 1 << k;
    }

    int lane = t & 63, w = t >> 6;
    int mrow = lane & 15, quad = lane >> 4;

    // A-fragments DIRECT from x: lane (c = w*16+mrow) reads 8 consecutive
    // floats of row (bi*16 + ks*2 + (quad>>1)), cols bj*16 + (quad&1)*8.
    // Bit-identical to the old LDS-staged xbf values.
    short8 areg[8];
    {
      int c = w * 16 + mrow;
      const float* xrow = x + ((long)(b * 64 + c) << 16) + bi * 4096 +
                          (quad >> 1) * 256 + bj * 16 + ((quad & 1) << 3);
#pragma unroll
      for (int ks = 0; ks < 8; ks++) {
        float4 lo = *(const float4*)(xrow + ks * 512);
        float4 hi = *(const float4*)(xrow + ks * 512 + 4);
        short8 a;
        a[0] = (short)f2bf(lo.x); a[1] = (short)f2bf(lo.y);
        a[2] = (short)f2bf(lo.z); a[3] = (short)f2bf(lo.w);
        a[4] = (short)f2bf(hi.x); a[5] = (short)f2bf(hi.y);
        a[6] = (short)f2bf(hi.z); a[7] = (short)f2bf(hi.w);
        areg[ks] = a;
      }
    }

    // f32 dot: thread t = pixel (r=t>>4, col=t&15) of the tile
    int r = t >> 4, col = t & 15;
    const float* base = x + ((long)(b * 64) << 16) + ((bi * 16 + r) << 8) + (bj * 16 + col);
    float acc[9];
#pragma unroll
    for (int k = 0; k < 9; k++) acc[k] = 0.f;
#pragma unroll 8
    for (int c = 0; c < 64; c++) {
      float xv = base[(long)c << 16];
#pragma unroll
      for (int k = 0; k < 9; k++) acc[k] = fmaf(xv, cent_s[k * 64 + c], acc[k]);
    }
    float mx = -1e30f;
#pragma unroll
    for (int k = 0; k < 9; k++) {
      float l = 2.f * acc[k] - c2_s[k];
      acc[k] = ((vbits >> k) & 1) ? l : -1e30f;
      mx = fmaxf(mx, acc[k]);
    }
    float sum = 0.f;
#pragma unroll
    for (int k = 0; k < 9; k++) {
      acc[k] = __expf(acc[k] - mx);
      sum += acc[k];
    }
    float rs = 1.f / sum;
#pragma unroll
    for (int k = 0; k < 9; k++) {
      acc[k] *= rs;
      affbf[k * 264 + t] = f2bf(acc[k]);
    }

#pragma unroll
    for (int k = 0; k < 9; k++) {
      float v = acc[k];
      v += __shfl_xor(v, 1);
      v += __shfl_xor(v, 2);
      v += __shfl_xor(v, 4);
      v += __shfl_xor(v, 8);
      v += __shfl_xor(v, 16);
      v += __shfl_xor(v, 32);
      if (lane == 0) den_s[w * 9 + k] = v;
    }
    __syncthreads();
    if (t < 9) {
      float d = den_s[t] + den_s[9 + t] + den_s[18 + t] + den_s[27 + t];
      int sc = scand[t]; sc = sc >= 0 ? sc : (-1 - sc);
      atomicAdd(&den[(b << 8) + sc], d);
    }

    // num GEMM: wave w owns c-tile [16w,16w+16); A from regs, B from LDS
    f32x4 dacc = {0.f, 0.f, 0.f, 0.f};
#pragma unroll
    for (int ks = 0; ks < 8; ks++) {
      int p0 = ks * 32 + quad * 8;
      short8 bf = *(const short8*)&affbf[mrow * 264 + p0];
      dacc = __builtin_amdgcn_mfma_f32_16x16x32_bf16(areg[ks], bf, dacc, 0, 0, 0);
    }
    int kcol = lane & 15;
    if (kcol < 9) {
      int sc = scand[kcol]; sc = sc >= 0 ? sc : (-1 - sc);
      float* np = num + (((b << 8) + sc) << 6) + w * 16 + quad * 4;
      atomicAdd(&np[0], dacc[0]);
      atomicAdd(&np[1], dacc[1]);
      atomicAdd(&np[2], dacc[2]);
      atomicAdd(&np[3], dacc[3]);
    }
  }

  gridbar(bar + 1, (int)gridDim.x);

  // ================= phase 2: out (one block per row, all 256 planes) =====
  {
    float* cent_s = (float*)smem;                 // 48*68 f32 = 13056B
    float* aff_t = (float*)(smem + 13056);        // 9*260 f32 = 9360B
    float* c2p = (float*)(smem + 22416);          // 384 f32
    float* den_s = (float*)(smem + 23952);        // 48 f32
    float* c2_s = (float*)(smem + 24144);         // 48 f32

    int i = wg & 255, b = wg >> 8;
    int bi = i >> 4;

    if (t < 48) {
      int ci = min(max(bi - 1 + (t >> 4), 0), 15);
      int cj = t & 15;
      den_s[t] = den[(b << 8) + ci * 16 + cj] + 1e-16f;
    }
    __syncthreads();
    for (int o = t; o < 768; o += 256) {
      int lr = o >> 4, f4i = o & 15;
      int ci = min(max(bi - 1 + (lr >> 4), 0), 15);
      int cj = lr & 15;
      float4 v = *(const float4*)(num + (((b << 8) + ci * 16 + cj) << 6) + f4i * 4);
      float inv = 1.f / den_s[lr];
      v.x *= inv; v.y *= inv; v.z *= inv; v.w *= inv;
      *(float4*)&cent_s[lr * 68 + f4i * 4] = v;
    }
    __syncthreads();
    for (int o = t; o < 384; o += 256) {
      int lr = o >> 3, pt = o & 7;
      float s = 0.f;
#pragma unroll
      for (int m = 0; m < 8; m++) { float v = cent_s[lr * 68 + pt * 8 + m]; s += v * v; }
      c2p[o] = s;
    }
    __syncthreads();
    if (t < 48) {
      float s = 0.f;
#pragma unroll
      for (int m = 0; m < 8; m++) s += c2p[t * 8 + m];
      c2_s[t] = s;
    }
    __syncthreads();

    int j = t, bj = j >> 4;
    int cidx[9];
    float c2k[9];
    int vbits = 0;
#pragma unroll
    for (int k = 0; k < 9; k++) {
      int di = k / 3 - 1, dj = k % 3 - 1;
      int ciu = bi + di, cju = bj + dj;
      if ((unsigned)ciu < 16u && (unsigned)cju < 16u) vbits |= 1 << k;
      int lidx = (di + 1) * 16 + min(max(cju, 0), 15);
      cidx[k] = lidx * 68;
      c2k[k] = c2_s[lidx];
    }
    const float* base = x + ((long)(b * 64) << 16) + (i << 8) + j;
    float acc[9];
#pragma unroll
    for (int k = 0; k < 9; k++) acc[k] = 0.f;
#pragma unroll 8
    for (int c = 0; c < 64; c++) {
      float xv = base[(long)c << 16];
#pragma unroll
      for (int k = 0; k < 9; k++) acc[k] = fmaf(xv, cent_s[cidx[k] + c], acc[k]);
    }
    float mx = -1e30f;
#pragma unroll
    for (int k = 0; k < 9; k++) {
      float l = 2.f * acc[k] - c2k[k];
      acc[k] = ((vbits >> k) & 1) ? l : -1e30f;
      mx = fmaxf(mx, acc[k]);
    }
    float sum = 0.f;
#pragma unroll
    for (int k = 0; k < 9; k++) {
      acc[k] = __expf(acc[k] - mx);
      sum += acc[k];
    }
    float rs = 1.f / sum;
#pragma unroll
    for (int k = 0; k < 9; k++) aff_t[k * 260 + j] = acc[k] * rs;
    __syncthreads();

    f32x4* obase = (f32x4*)out + ((long)(b << 8) << 14) + (i << 6) + (t & 63);
    int j4 = t & 63;
    int w2 = t >> 6;
#pragma unroll 4
    for (int m = 0; m < 64; m++) {
      int s = (m << 2) | w2;
      f32x4 v = {0.f, 0.f, 0.f, 0.f};
      int di = (s >> 4) - bi;
      if ((unsigned)(di + 1) <= 2u) {
        int dj = (s & 15) - (j4 >> 2);
        if ((unsigned)(dj + 1) <= 2u) {
          int k = (di + 1) * 3 + dj + 1;
          v = *(const f32x4*)&aff_t[k * 260 + (j4 << 2)];
        }
      }
      __builtin_nontemporal_store(v, &obase[(long)s << 14]);
    }
  }
}

// ======================= fallback: exact R0 pipeline ========================
__global__ __launch_bounds__(256) void k_init(const float* __restrict__ x,
                                              float* __restrict__ cent0,
                                              float4* __restrict__ zero4) {
  __shared__ float blk[64];
  int t = threadIdx.x;
  int wg = blockIdx.x;
  int cg = wg & 15, bi = (wg >> 4) & 15, b = wg >> 8;
  int tid = wg * 256 + t;
  if (tid < 16640) zero4[tid] = make_float4(0.f, 0.f, 0.f, 0.f);
  if (t < 64) blk[t] = 0.f;
  __syncthreads();
  int sub = t >> 6, j4 = t & 63;
#pragma unroll
  for (int q = 0; q < 4; q++) {
    int c = cg * 4 + q;
    const float4* xp4 =
        (const float4*)(x + ((long)(b * 64 + c) << 16) + ((bi * 16 + sub * 4) << 8)) + j4;
    float4 a = make_float4(0.f, 0.f, 0.f, 0.f);
#pragma unroll
    for (int r = 0; r < 4; r++) {
      float4 v = xp4[r * 64];
      a.x += v.x; a.y += v.y; a.z += v.z; a.w += v.w;
    }
    float ps = a.x + a.y + a.z + a.w;
    ps += __shfl_xor(ps, 1);
    ps += __shfl_xor(ps, 2);
    if ((j4 & 3) == 0) atomicAdd(&blk[(j4 >> 2) * 4 + q], ps);
  }
  __syncthreads();
  if (t < 64) {
    int sj = t >> 2, q = t & 3;
    cent0[(((b << 8) + bi * 16 + sj) << 6) + cg * 4 + q] = blk[t] * (1.f / 256.f);
  }
}

__global__ __launch_bounds__(256) void k_stat(const float* __restrict__ x,
                                              const float* __restrict__ cent,
                                              float* __restrict__ num,
                                              float* __restrict__ den) {
  __shared__ __align__(16) unsigned short xbf[64 * 264];
  __shared__ __align__(16) unsigned short affbf[16 * 264];
  __shared__ float cent_s[9 * 64];
  __shared__ float c2p[72];
  __shared__ float c2_s[9];
  __shared__ float den_s[36];
  __shared__ int scand[9];

  int t = threadIdx.x;
  int wg = blockIdx.x;
  int bj = wg & 15, bi = (wg >> 4) & 15, b = wg >> 8;

  if (t < 9) {
    int di = t / 3 - 1, dj = t % 3 - 1;
    int ci = bi + di, cj = bj + dj;
    int sc = min(max(ci, 0), 15) * 16 + min(max(cj, 0), 15);
    bool valid = ((unsigned)ci < 16u) && ((unsigned)cj < 16u);
    scand[t] = valid ? sc : (-1 - sc);
  }
  for (int o = t; o < 144; o += 256) {
    int k = o >> 4, f4 = o & 15;
    int di = k / 3 - 1, dj = k % 3 - 1;
    int sc = min(max(bi + di, 0), 15) * 16 + min(max(bj + dj, 0), 15);
    *(float4*)&cent_s[k * 64 + f4 * 4] =
        *(const float4*)(cent + (((b << 8) + sc) << 6) + f4 * 4);
  }
  __syncthreads();
  if (t < 72) {
    int k = t >> 3, pt = t & 7;
    float s = 0.f;
#pragma unroll
    for (int m = 0; m < 8; m++) { float v = cent_s[k * 64 + pt * 8 + m]; s += v * v; }
    c2p[t] = s;
  }
  __syncthreads();
  if (t < 9) {
    float s = 0.f;
#pragma unroll
    for (int m = 0; m < 8; m++) s += c2p[t * 8 + m];
    c2_s[t] = s;
  }
  __syncthreads();

  int vbits = 0;
#pragma unroll
  for (int k = 0; k < 9; k++) {
    int ci = bi + k / 3 - 1, cj = bj + k % 3 - 1;
    if ((unsigned)ci < 16u && (unsigned)cj < 16u) vbits |= 1 << k;
  }

  int r = t >> 4, col = t & 15;
  const float* base = x + ((long)(b * 64) << 16) + ((bi * 16 + r) << 8) + (bj * 16 + col);
  float acc[9];
#pragma unroll
  for (int k = 0; k < 9; k++) acc[k] = 0.f;
#pragma unroll 8
  for (int c = 0; c < 64; c++) {
    float xv = base[(long)c << 16];
    xbf[c * 264 + t] = f2bf(xv);
#pragma unroll
    for (int k = 0; k < 9; k++) acc[k] = fmaf(xv, cent_s[k * 64 + c], acc[k]);
  }
  float mx = -1e30f;
#pragma unroll
  for (int k = 0; k < 9; k++) {
    float l = 2.f * acc[k] - c2_s[k];
    acc[k] = ((vbits >> k) & 1) ? l : -1e30f;
    mx = fmaxf(mx, acc[k]);
  }
  float sum = 0.f;
#pragma unroll
  for (int k = 0; k < 9; k++) {
    acc[k] = __expf(acc[k] - mx);
    sum += acc[k];
  }
  float rs = 1.f / sum;
#pragma unroll
  for (int k = 0; k < 9; k++) {
    acc[k] *= rs;
    affbf[k * 264 + t] = f2bf(acc[k]);
  }

  int lane = t & 63, w = t >> 6;
#pragma unroll
  for (int k = 0; k < 9; k++) {
    float v = acc[k];
    v += __shfl_xor(v, 1);
    v += __shfl_xor(v, 2);
    v += __shfl_xor(v, 4);
    v += __shfl_xor(v, 8);
    v += __shfl_xor(v, 16);
    v += __shfl_xor(v, 32);
    if (lane == 0) den_s[w * 9 + k] = v;
  }
  __syncthreads();
  if (t < 9) {
    float d = den_s[t] + den_s[9 + t] + den_s[18 + t] + den_s[27 + t];
    int sc = scand[t]; sc = sc >= 0 ? sc : (-1 - sc);
    atomicAdd(&den[(b << 8) + sc], d);
  }

  int mrow = lane & 15;
  int quad = lane >> 4;
  f32x4 dacc = {0.f, 0.f, 0.f, 0.f};
#pragma unroll
  for (int ks = 0; ks < 8; ks++) {
    int p0 = ks * 32 + quad * 8;
    short8 a = *(const short8*)&xbf[(w * 16 + mrow) * 264 + p0];
    short8 bf = *(const short8*)&affbf[mrow * 264 + p0];
    dacc = __builtin_amdgcn_mfma_f32_16x16x32_bf16(a, bf, dacc, 0, 0, 0);
  }
  int kcol = lane & 15;
  if (kcol < 9) {
    int sc = scand[kcol]; sc = sc >= 0 ? sc : (-1 - sc);
    float* np = num + (((b << 8) + sc) << 6) + w * 16 + quad * 4;
    atomicAdd(&np[0], dacc[0]);
    atomicAdd(&np[1], dacc[1]);
    atomicAdd(&np[2], dacc[2]);
    atomicAdd(&np[3], dacc[3]);
  }
}

__global__ __launch_bounds__(256) void k_out(const float* __restrict__ x,
                                             const float* __restrict__ num,
                                             const float* __restrict__ den,
                                             f32x4* __restrict__ out4) {
  __shared__ float cent_s[48 * 68];
  __shared__ float den_s[48];
  __shared__ float c2p[384];
  __shared__ float c2_s[48];
  __shared__ float aff_t[9 * 260];

  int t = threadIdx.x;
  int wg = blockIdx.x;
  int h = wg & 1, i = (wg >> 1) & 255, b = wg >> 9;
  int bi = i >> 4;

  if (t < 48) {
    int ci = min(max(bi - 1 + (t >> 4), 0), 15);
    int cj = t & 15;
    den_s[t] = den[(b << 8) + ci * 16 + cj] + 1e-16f;
  }
  __syncthreads();
  for (int o = t; o < 768; o += 256) {
    int lr = o >> 4, f4i = o & 15;
    int ci = min(max(bi - 1 + (lr >> 4), 0), 15);
    int cj = lr & 15;
    float4 v = *(const float4*)(num + (((b << 8) + ci * 16 + cj) << 6) + f4i * 4);
    float inv = 1.f / den_s[lr];
    v.x *= inv; v.y *= inv; v.z *= inv; v.w *= inv;
    *(float4*)&cent_s[lr * 68 + f4i * 4] = v;
  }
  __syncthreads();
  for (int o = t; o < 384; o += 256) {
    int lr = o >> 3, pt = o & 7;
    float s = 0.f;
#pragma unroll
    for (int m = 0; m < 8; m++) { float v = cent_s[lr * 68 + pt * 8 + m]; s += v * v; }
    c2p[o] = s;
  }
  __syncthreads();
  if (t < 48) {
    float s = 0.f;
#pragma unroll
    for (int m = 0; m < 8; m++) s += c2p[t * 8 + m];
    c2_s[t] = s;
  }
  __syncthreads();

  int j = t, bj = j >> 4;
  int cidx[9];
  float c2k[9];
  int vbits = 0;
#pragma unroll
  for (int k = 0; k < 9; k++) {
    int di = k / 3 - 1, dj = k % 3 - 1;
    int ciu = bi + di, cju = bj + dj;
    if ((unsigned)ciu < 16u && (unsigned)cju < 16u) vbits |= 1 << k;
    int lidx = (di + 1) * 16 + min(max(cju, 0), 15);
    cidx[k] = lidx * 68;
    c2k[k] = c2_s[lidx];
  }
  const float* base = x + ((long)(b * 64) << 16) + (i << 8) + j;
  float acc[9];
#pragma unroll
  for (int k = 0; k < 9; k++) acc[k] = 0.f;
#pragma unroll 8
  for (int c = 0; c < 64; c++) {
    float xv = base[(long)c << 16];
#pragma unroll
    for (int k = 0; k < 9; k++) acc[k] = fmaf(xv, cent_s[cidx[k] + c], acc[k]);
  }
  float mx = -1e30f;
#pragma unroll
  for (int k = 0; k < 9; k++) {
    float l = 2.f * acc[k] - c2k[k];
    acc[k] = ((vbits >> k) & 1) ? l : -1e30f;
    mx = fmaxf(mx, acc[k]);
  }
  float sum = 0.f;
#pragma unroll
  for (int k = 0; k < 9; k++) {
    acc[k] = __expf(acc[k] - mx);
    sum += acc[k];
  }
  float rs = 1.f / sum;
#pragma unroll
  for (int k = 0; k < 9; k++) aff_t[k * 260 + j] = acc[k] * rs;
  __syncthreads();

  f32x4* obase = out4 + ((long)(b << 8) << 14) + (i << 6) + (t & 63);
  int j4 = t & 63;
  int w = t >> 6;
  int s0 = h << 7;
#pragma unroll 4
  for (int m = 0; m < 32; m++) {
    int s = s0 | (m << 2) | w;
    f32x4 v = {0.f, 0.f, 0.f, 0.f};
    int di = (s >> 4) - bi;
    if ((unsigned)(di + 1) <= 2u) {
      int dj = (s & 15) - (j4 >> 2);
      if ((unsigned)(dj + 1) <= 2u) {
        int k = (di + 1) * 3 + dj + 1;
        v = *(const f32x4*)&aff_t[k * 260 + (j4 << 2)];
      }
    }
    __builtin_nontemporal_store(v, &obase[(long)s << 14]);
  }
}

extern "C" void kernel_launch(void* const* d_in, const int* in_sizes, int n_in,
                              void* d_out, int out_size, void* d_ws, size_t ws_size,
                              hipStream_t stream) {
  const float* x = (const float*)d_in[0];
  float* out = (float*)d_out;
  float* ws = (float*)d_ws;

  float* num   = ws;
  float* den   = ws + 65536;
  float* cent0 = ws + 66560;
  int* bar     = (int*)(ws + 132096);

  k_zero<<<1, 64, 0, stream>>>(bar);

  void* args[] = {(void*)&x, (void*)&ws, (void*)&out, (void*)&bar};
  hipError_t e = hipLaunchCooperativeKernel((const void*)k_fused, dim3(1024),
                                            dim3(256), args, 0, stream);
  if (e != hipSuccess) {
    (void)hipGetLastError();  // clear sticky error, take proven R0 path
    k_init<<<1024, 256, 0, stream>>>(x, cent0, (float4*)ws);
    k_stat<<<1024, 256, 0, stream>>>(x, cent0, num, den);
    k_out<<<2048, 256, 0, stream>>>(x, num, den, (f32x4*)out);
  }
}

// Round 5
// 365.988 us; speedup vs baseline: 2.1260x; 2.1260x over previous
//
#include <hip/hip_runtime.h>

// GenSP: B=4, C=64, H=W=256, st=16 -> nH=nW=16, nS=256, P=65536
// out (B,nS,P) = 256MB dense, <=9 nonzeros per pixel column.
// M_COEF=0 -> grid channels zero; f2 (pixel norm) cancels in softmax.
//
// R5 structure (from R4 counters: 484MB total HBM traffic, nothing saturated
// -> stall-bound; the 256MB scattered nt plane-writes are the pathology):
//   k_init2 (2048 blocks): [0,1024) = R0 k_init (block means, zero num/den);
//                          [1024,2048) = contiguous zero-fill of the whole
//                          256MB output at fill-kernel rate (plain stores).
//   k_stat  (1024 blocks): unchanged R0 (LDS-staged bf16 MFMA num, den).
//   k_strip (1024 blocks): one block per (b,row): finalize 48 cents,
//                          per-pixel 9-way softmax ONCE (no h-dup), then
//                          store ONLY the nonzero strips (<=576 f32x4 per
//                          block, 64B-aligned segments) straight from LDS.
//   Stream order guarantees strips overwrite the zero background; 9.4MB of
//   bytes written twice, zero race (different kernels).
// ws float layout: num[65536] den[1024] cent0[65536]

typedef __attribute__((ext_vector_type(8))) short short8;
typedef __attribute__((ext_vector_type(4))) float f32x4;

__device__ __forceinline__ unsigned short f2bf(float f) {
  unsigned u = __float_as_uint(f);
  u += 0x7fff + ((u >> 16) & 1);   // round-nearest-even
  return (unsigned short)(u >> 16);
}

// ---- init + background zero-fill ----
__global__ __launch_bounds__(256) void k_init2(const float* __restrict__ x,
                                               float* __restrict__ cent0,
                                               float4* __restrict__ zero4,
                                               f32x4* __restrict__ out4) {
  __shared__ float blk[64];
  int t = threadIdx.x;
  int wg = blockIdx.x;

  if (wg >= 1024) {
    // zero-writer: plane q, 256KB contiguous (fill-kernel pattern)
    int q = wg - 1024;
    f32x4* op = out4 + ((long)q << 14);
    const f32x4 z = {0.f, 0.f, 0.f, 0.f};
#pragma unroll 8
    for (int m = 0; m < 64; m++) op[m * 256 + t] = z;
    return;
  }

  int cg = wg & 15, bi = (wg >> 4) & 15, b = wg >> 8;
  int tid = wg * 256 + t;
  if (tid < 16640) zero4[tid] = make_float4(0.f, 0.f, 0.f, 0.f);  // num+den
  if (t < 64) blk[t] = 0.f;
  __syncthreads();
  int sub = t >> 6, j4 = t & 63;
#pragma unroll
  for (int q = 0; q < 4; q++) {
    int c = cg * 4 + q;
    const float4* xp4 =
        (const float4*)(x + ((long)(b * 64 + c) << 16) + ((bi * 16 + sub * 4) << 8)) + j4;
    float4 a = make_float4(0.f, 0.f, 0.f, 0.f);
#pragma unroll
    for (int r = 0; r < 4; r++) {
      float4 v = xp4[r * 64];
      a.x += v.x; a.y += v.y; a.z += v.z; a.w += v.w;
    }
    float ps = a.x + a.y + a.z + a.w;
    ps += __shfl_xor(ps, 1);
    ps += __shfl_xor(ps, 2);
    if ((j4 & 3) == 0) atomicAdd(&blk[(j4 >> 2) * 4 + q], ps);
  }
  __syncthreads();
  if (t < 64) {
    int sj = t >> 2, q = t & 3;
    cent0[(((b << 8) + bi * 16 + sj) << 6) + cg * 4 + q] = blk[t] * (1.f / 256.f);
  }
}

// ---- stat: unchanged from R0 (proven) ----
__global__ __launch_bounds__(256) void k_stat(const float* __restrict__ x,
                                              const float* __restrict__ cent,
                                              float* __restrict__ num,
                                              float* __restrict__ den) {
  __shared__ __align__(16) unsigned short xbf[64 * 264];
  __shared__ __align__(16) unsigned short affbf[16 * 264];
  __shared__ float cent_s[9 * 64];
  __shared__ float c2p[72];
  __shared__ float c2_s[9];
  __shared__ float den_s[36];
  __shared__ int scand[9];

  int t = threadIdx.x;
  int wg = blockIdx.x;            // b*256 + bi*16 + bj
  int bj = wg & 15, bi = (wg >> 4) & 15, b = wg >> 8;

  if (t < 9) {
    int di = t / 3 - 1, dj = t % 3 - 1;
    int ci = bi + di, cj = bj + dj;
    int sc = min(max(ci, 0), 15) * 16 + min(max(cj, 0), 15);
    bool valid = ((unsigned)ci < 16u) && ((unsigned)cj < 16u);
    scand[t] = valid ? sc : (-1 - sc);
  }
  for (int o = t; o < 144; o += 256) {
    int k = o >> 4, f4 = o & 15;
    int di = k / 3 - 1, dj = k % 3 - 1;
    int sc = min(max(bi + di, 0), 15) * 16 + min(max(bj + dj, 0), 15);
    *(float4*)&cent_s[k * 64 + f4 * 4] =
        *(const float4*)(cent + (((b << 8) + sc) << 6) + f4 * 4);
  }
  __syncthreads();
  if (t < 72) {
    int k = t >> 3, pt = t & 7;
    float s = 0.f;
#pragma unroll
    for (int m = 0; m < 8; m++) { float v = cent_s[k * 64 + pt * 8 + m]; s += v * v; }
    c2p[t] = s;
  }
  __syncthreads();
  if (t < 9) {
    float s = 0.f;
#pragma unroll
    for (int m = 0; m < 8; m++) s += c2p[t * 8 + m];
    c2_s[t] = s;
  }
  __syncthreads();

  int vbits = 0;
#pragma unroll
  for (int k = 0; k < 9; k++) {
    int ci = bi + k / 3 - 1, cj = bj + k % 3 - 1;
    if ((unsigned)ci < 16u && (unsigned)cj < 16u) vbits |= 1 << k;
  }

  int r = t >> 4, col = t & 15;
  const float* base = x + ((long)(b * 64) << 16) + ((bi * 16 + r) << 8) + (bj * 16 + col);
  float acc[9];
#pragma unroll
  for (int k = 0; k < 9; k++) acc[k] = 0.f;
#pragma unroll 8
  for (int c = 0; c < 64; c++) {
    float xv = base[(long)c << 16];
    xbf[c * 264 + t] = f2bf(xv);
#pragma unroll
    for (int k = 0; k < 9; k++) acc[k] = fmaf(xv, cent_s[k * 64 + c], acc[k]);
  }
  float mx = -1e30f;
#pragma unroll
  for (int k = 0; k < 9; k++) {
    float l = 2.f * acc[k] - c2_s[k];
    acc[k] = ((vbits >> k) & 1) ? l : -1e30f;
    mx = fmaxf(mx, acc[k]);
  }
  float sum = 0.f;
#pragma unroll
  for (int k = 0; k < 9; k++) {
    acc[k] = __expf(acc[k] - mx);
    sum += acc[k];
  }
  float rs = 1.f / sum;
#pragma unroll
  for (int k = 0; k < 9; k++) {
    acc[k] *= rs;
    affbf[k * 264 + t] = f2bf(acc[k]);
  }

  int lane = t & 63, w = t >> 6;
#pragma unroll
  for (int k = 0; k < 9; k++) {
    float v = acc[k];
    v += __shfl_xor(v, 1);
    v += __shfl_xor(v, 2);
    v += __shfl_xor(v, 4);
    v += __shfl_xor(v, 8);
    v += __shfl_xor(v, 16);
    v += __shfl_xor(v, 32);
    if (lane == 0) den_s[w * 9 + k] = v;
  }
  __syncthreads();
  if (t < 9) {
    float d = den_s[t] + den_s[9 + t] + den_s[18 + t] + den_s[27 + t];
    int sc = scand[t]; sc = sc >= 0 ? sc : (-1 - sc);
    atomicAdd(&den[(b << 8) + sc], d);
  }

  int mrow = lane & 15;
  int quad = lane >> 4;
  f32x4 dacc = {0.f, 0.f, 0.f, 0.f};
#pragma unroll
  for (int ks = 0; ks < 8; ks++) {
    int p0 = ks * 32 + quad * 8;
    short8 a = *(const short8*)&xbf[(w * 16 + mrow) * 264 + p0];
    short8 bf = *(const short8*)&affbf[mrow * 264 + p0];
    dacc = __builtin_amdgcn_mfma_f32_16x16x32_bf16(a, bf, dacc, 0, 0, 0);
  }
  int kcol = lane & 15;
  if (kcol < 9) {
    int sc = scand[kcol]; sc = sc >= 0 ? sc : (-1 - sc);
    float* np = num + (((b << 8) + sc) << 6) + w * 16 + quad * 4;
    atomicAdd(&np[0], dacc[0]);
    atomicAdd(&np[1], dacc[1]);
    atomicAdd(&np[2], dacc[2]);
    atomicAdd(&np[3], dacc[3]);
  }
}

// ---- strip: one block per (b,row); affinity once; store only nonzeros ----
__global__ __launch_bounds__(256) void k_strip(const float* __restrict__ x,
                                               const float* __restrict__ num,
                                               const float* __restrict__ den,
                                               f32x4* __restrict__ out4) {
  __shared__ __align__(16) float cent_s[48 * 68];
  __shared__ __align__(16) float aff_t[9 * 260];
  __shared__ float c2p[384];
  __shared__ float den_s[48];
  __shared__ float c2_s[48];

  int t = threadIdx.x;
  int wg = blockIdx.x;            // b*256 + i
  int i = wg & 255, b = wg >> 8;
  int bi = i >> 4;

  if (t < 48) {
    int ci = min(max(bi - 1 + (t >> 4), 0), 15);
    int cj = t & 15;
    den_s[t] = den[(b << 8) + ci * 16 + cj] + 1e-16f;
  }
  __syncthreads();
  for (int o = t; o < 768; o += 256) {
    int lr = o >> 4, f4i = o & 15;
    int ci = min(max(bi - 1 + (lr >> 4), 0), 15);
    int cj = lr & 15;
    float4 v = *(const float4*)(num + (((b << 8) + ci * 16 + cj) << 6) + f4i * 4);
    float inv = 1.f / den_s[lr];
    v.x *= inv; v.y *= inv; v.z *= inv; v.w *= inv;
    *(float4*)&cent_s[lr * 68 + f4i * 4] = v;
  }
  __syncthreads();
  for (int o = t; o < 384; o += 256) {
    int lr = o >> 3, pt = o & 7;
    float s = 0.f;
#pragma unroll
    for (int m = 0; m < 8; m++) { float v = cent_s[lr * 68 + pt * 8 + m]; s += v * v; }
    c2p[o] = s;
  }
  __syncthreads();
  if (t < 48) {
    float s = 0.f;
#pragma unroll
    for (int m = 0; m < 8; m++) s += c2p[t * 8 + m];
    c2_s[t] = s;
  }
  __syncthreads();

  int j = t, bj = j >> 4;
  int cidx[9];
  float c2k[9];
  int vbits = 0;
#pragma unroll
  for (int k = 0; k < 9; k++) {
    int di = k / 3 - 1, dj = k % 3 - 1;
    int ciu = bi + di, cju = bj + dj;
    if ((unsigned)ciu < 16u && (unsigned)cju < 16u) vbits |= 1 << k;
    int lidx = (di + 1) * 16 + min(max(cju, 0), 15);
    cidx[k] = lidx * 68;
    c2k[k] = c2_s[lidx];
  }
  const float* base = x + ((long)(b * 64) << 16) + (i << 8) + j;
  float acc[9];
#pragma unroll
  for (int k = 0; k < 9; k++) acc[k] = 0.f;
#pragma unroll 8
  for (int c = 0; c < 64; c++) {
    float xv = base[(long)c << 16];
#pragma unroll
    for (int k = 0; k < 9; k++) acc[k] = fmaf(xv, cent_s[cidx[k] + c], acc[k]);
  }
  float mx = -1e30f;
#pragma unroll
  for (int k = 0; k < 9; k++) {
    float l = 2.f * acc[k] - c2k[k];
    acc[k] = ((vbits >> k) & 1) ? l : -1e30f;
    mx = fmaxf(mx, acc[k]);
  }
  float sum = 0.f;
#pragma unroll
  for (int k = 0; k < 9; k++) {
    acc[k] = __expf(acc[k] - mx);
    sum += acc[k];
  }
  float rs = 1.f / sum;
#pragma unroll
  for (int k = 0; k < 9; k++) aff_t[k * 260 + j] = acc[k] * rs;
  __syncthreads();

  // strip stores: work item o in [0,576): si_idx = o/192, sj = (o%192)/12,
  // u4 = o%12 -> j4 = 4*sj - 4 + u4. plane s = (bi-1+si_idx)*16 + sj,
  // k = si_idx*3 + (sj - (j4>>2)) + 1. 64B-aligned 16B stores, value from LDS.
  long obase = ((long)(b << 8)) << 14;
#pragma unroll
  for (int step = 0; step < 3; step++) {
    int o = step * 256 + t;
    if (o >= 576) break;
    int si_idx = o / 192;
    int rem = o - si_idx * 192;
    int sj = rem / 12;
    int u4 = rem - sj * 12;
    int si = bi - 1 + si_idx;
    int j4 = 4 * sj - 4 + u4;
    if ((unsigned)si < 16u && (unsigned)j4 < 64u) {
      int k = si_idx * 3 + (sj - (j4 >> 2)) + 1;
      f32x4 v = *(const f32x4*)&aff_t[k * 260 + (j4 << 2)];
      int s = si * 16 + sj;
      out4[obase + ((long)s << 14) + (i << 6) + j4] = v;
    }
  }
}

extern "C" void kernel_launch(void* const* d_in, const int* in_sizes, int n_in,
                              void* d_out, int out_size, void* d_ws, size_t ws_size,
                              hipStream_t stream) {
  const float* x = (const float*)d_in[0];
  float* out = (float*)d_out;
  float* ws = (float*)d_ws;

  float* num   = ws;
  float* den   = ws + 65536;
  float* cent0 = ws + 66560;

  k_init2<<<2048, 256, 0, stream>>>(x, cent0, (float4*)ws, (f32x4*)out);
  k_stat<<<1024, 256, 0, stream>>>(x, cent0, num, den);
  k_strip<<<1024, 256, 0, stream>>>(x, num, den, (f32x4*)out);
}

// Round 6
// 356.489 us; speedup vs baseline: 2.1827x; 1.0266x over previous
//
#include <hip/hip_runtime.h>

// GenSP: B=4, C=64, H=W=256, st=16 -> nH=nW=16, nS=256, P=65536
// out (B,nS,P) = 256MB dense, <=9 nonzeros per pixel column.
// M_COEF=0 -> grid channels zero; f2 (pixel norm) cancels in softmax.
//
// R6: overlap the zero background with stat.
//   k_init  (1024 blocks): R0 k_init exactly (block means, zero num/den).
//   k_statz (2048 blocks): [0,1024) = R0 k_stat exactly (LDS bf16 MFMA num,
//            den atomics); [1024,2048) = 256MB output zero-fill, one plane
//            per block, contiguous NT stores (no L2/L3 pollution -> x stays
//            cache-resident for stat and strip reads; fill has no deps so it
//            rides in stat's memory-bandwidth shadow).
//   k_strip (1024 blocks): R5 k_strip exactly (affinity once per row, store
//            only the <=9.4MB nonzero strips; stream order makes the
//            overwrite of the zero background race-free).
// Evidence: R0..R5 all within +-4% of ~365us; R4 decomposition shows ~250us
// fixed harness overhead; this targets the last ~45us of serialized fill +
// cache thrash. ws float layout: num[65536] den[1024] cent0[65536]

typedef __attribute__((ext_vector_type(8))) short short8;
typedef __attribute__((ext_vector_type(4))) float f32x4;

__device__ __forceinline__ unsigned short f2bf(float f) {
  unsigned u = __float_as_uint(f);
  u += 0x7fff + ((u >> 16) & 1);   // round-nearest-even
  return (unsigned short)(u >> 16);
}

// ---- init: 16x16 block means -> cent0; zero num/den (R0 exact) ----
__global__ __launch_bounds__(256) void k_init(const float* __restrict__ x,
                                              float* __restrict__ cent0,
                                              float4* __restrict__ zero4) {
  __shared__ float blk[64];
  int t = threadIdx.x;
  int wg = blockIdx.x;
  int cg = wg & 15, bi = (wg >> 4) & 15, b = wg >> 8;
  int tid = wg * 256 + t;
  if (tid < 16640) zero4[tid] = make_float4(0.f, 0.f, 0.f, 0.f);  // num+den
  if (t < 64) blk[t] = 0.f;
  __syncthreads();
  int sub = t >> 6, j4 = t & 63;
#pragma unroll
  for (int q = 0; q < 4; q++) {
    int c = cg * 4 + q;
    const float4* xp4 =
        (const float4*)(x + ((long)(b * 64 + c) << 16) + ((bi * 16 + sub * 4) << 8)) + j4;
    float4 a = make_float4(0.f, 0.f, 0.f, 0.f);
#pragma unroll
    for (int r = 0; r < 4; r++) {
      float4 v = xp4[r * 64];
      a.x += v.x; a.y += v.y; a.z += v.z; a.w += v.w;
    }
    float ps = a.x + a.y + a.z + a.w;
    ps += __shfl_xor(ps, 1);
    ps += __shfl_xor(ps, 2);
    if ((j4 & 3) == 0) atomicAdd(&blk[(j4 >> 2) * 4 + q], ps);
  }
  __syncthreads();
  if (t < 64) {
    int sj = t >> 2, q = t & 3;
    cent0[(((b << 8) + bi * 16 + sj) << 6) + cg * 4 + q] = blk[t] * (1.f / 256.f);
  }
}

// ---- statz: blocks [0,1024) = R0 k_stat; [1024,2048) = NT zero-fill ----
__global__ __launch_bounds__(256) void k_statz(const float* __restrict__ x,
                                               const float* __restrict__ cent,
                                               float* __restrict__ num,
                                               float* __restrict__ den,
                                               f32x4* __restrict__ out4) {
  __shared__ __align__(16) unsigned short xbf[64 * 264];
  __shared__ __align__(16) unsigned short affbf[16 * 264];
  __shared__ float cent_s[9 * 64];
  __shared__ float c2p[72];
  __shared__ float c2_s[9];
  __shared__ float den_s[36];
  __shared__ int scand[9];

  int t = threadIdx.x;
  int wg = blockIdx.x;

  if (wg >= 1024) {
    // zero-writer: one 256KB plane, contiguous NT stores (fill pattern,
    // bypasses L2/L3 so x stays cache-resident for concurrent stat blocks)
    int q = wg - 1024;                       // b*256 + s
    f32x4* op = out4 + ((long)q << 14);
    const f32x4 z = {0.f, 0.f, 0.f, 0.f};
#pragma unroll 8
    for (int m = 0; m < 64; m++)
      __builtin_nontemporal_store(z, &op[m * 256 + t]);
    return;
  }

  int bj = wg & 15, bi = (wg >> 4) & 15, b = wg >> 8;

  if (t < 9) {
    int di = t / 3 - 1, dj = t % 3 - 1;
    int ci = bi + di, cj = bj + dj;
    int sc = min(max(ci, 0), 15) * 16 + min(max(cj, 0), 15);
    bool valid = ((unsigned)ci < 16u) && ((unsigned)cj < 16u);
    scand[t] = valid ? sc : (-1 - sc);
  }
  for (int o = t; o < 144; o += 256) {
    int k = o >> 4, f4 = o & 15;
    int di = k / 3 - 1, dj = k % 3 - 1;
    int sc = min(max(bi + di, 0), 15) * 16 + min(max(bj + dj, 0), 15);
    *(float4*)&cent_s[k * 64 + f4 * 4] =
        *(const float4*)(cent + (((b << 8) + sc) << 6) + f4 * 4);
  }
  __syncthreads();
  if (t < 72) {
    int k = t >> 3, pt = t & 7;
    float s = 0.f;
#pragma unroll
    for (int m = 0; m < 8; m++) { float v = cent_s[k * 64 + pt * 8 + m]; s += v * v; }
    c2p[t] = s;
  }
  __syncthreads();
  if (t < 9) {
    float s = 0.f;
#pragma unroll
    for (int m = 0; m < 8; m++) s += c2p[t * 8 + m];
    c2_s[t] = s;
  }
  __syncthreads();

  int vbits = 0;
#pragma unroll
  for (int k = 0; k < 9; k++) {
    int ci = bi + k / 3 - 1, cj = bj + k % 3 - 1;
    if ((unsigned)ci < 16u && (unsigned)cj < 16u) vbits |= 1 << k;
  }

  int r = t >> 4, col = t & 15;
  const float* base = x + ((long)(b * 64) << 16) + ((bi * 16 + r) << 8) + (bj * 16 + col);
  float acc[9];
#pragma unroll
  for (int k = 0; k < 9; k++) acc[k] = 0.f;
#pragma unroll 8
  for (int c = 0; c < 64; c++) {
    float xv = base[(long)c << 16];
    xbf[c * 264 + t] = f2bf(xv);
#pragma unroll
    for (int k = 0; k < 9; k++) acc[k] = fmaf(xv, cent_s[k * 64 + c], acc[k]);
  }
  float mx = -1e30f;
#pragma unroll
  for (int k = 0; k < 9; k++) {
    float l = 2.f * acc[k] - c2_s[k];
    acc[k] = ((vbits >> k) & 1) ? l : -1e30f;
    mx = fmaxf(mx, acc[k]);
  }
  float sum = 0.f;
#pragma unroll
  for (int k = 0; k < 9; k++) {
    acc[k] = __expf(acc[k] - mx);
    sum += acc[k];
  }
  float rs = 1.f / sum;
#pragma unroll
  for (int k = 0; k < 9; k++) {
    acc[k] *= rs;
    affbf[k * 264 + t] = f2bf(acc[k]);
  }

  int lane = t & 63, w = t >> 6;
#pragma unroll
  for (int k = 0; k < 9; k++) {
    float v = acc[k];
    v += __shfl_xor(v, 1);
    v += __shfl_xor(v, 2);
    v += __shfl_xor(v, 4);
    v += __shfl_xor(v, 8);
    v += __shfl_xor(v, 16);
    v += __shfl_xor(v, 32);
    if (lane == 0) den_s[w * 9 + k] = v;
  }
  __syncthreads();
  if (t < 9) {
    float d = den_s[t] + den_s[9 + t] + den_s[18 + t] + den_s[27 + t];
    int sc = scand[t]; sc = sc >= 0 ? sc : (-1 - sc);
    atomicAdd(&den[(b << 8) + sc], d);
  }

  int mrow = lane & 15;
  int quad = lane >> 4;
  f32x4 dacc = {0.f, 0.f, 0.f, 0.f};
#pragma unroll
  for (int ks = 0; ks < 8; ks++) {
    int p0 = ks * 32 + quad * 8;
    short8 a = *(const short8*)&xbf[(w * 16 + mrow) * 264 + p0];
    short8 bf = *(const short8*)&affbf[mrow * 264 + p0];
    dacc = __builtin_amdgcn_mfma_f32_16x16x32_bf16(a, bf, dacc, 0, 0, 0);
  }
  int kcol = lane & 15;
  if (kcol < 9) {
    int sc = scand[kcol]; sc = sc >= 0 ? sc : (-1 - sc);
    float* np = num + (((b << 8) + sc) << 6) + w * 16 + quad * 4;
    atomicAdd(&np[0], dacc[0]);
    atomicAdd(&np[1], dacc[1]);
    atomicAdd(&np[2], dacc[2]);
    atomicAdd(&np[3], dacc[3]);
  }
}

// ---- strip: one block per (b,row); affinity once; store only nonzeros ----
// (R5 verified-passing body, unchanged)
__global__ __launch_bounds__(256) void k_strip(const float* __restrict__ x,
                                               const float* __restrict__ num,
                                               const float* __restrict__ den,
                                               f32x4* __restrict__ out4) {
  __shared__ __align__(16) float cent_s[48 * 68];
  __shared__ __align__(16) float aff_t[9 * 260];
  __shared__ float c2p[384];
  __shared__ float den_s[48];
  __shared__ float c2_s[48];

  int t = threadIdx.x;
  int wg = blockIdx.x;            // b*256 + i
  int i = wg & 255, b = wg >> 8;
  int bi = i >> 4;

  if (t < 48) {
    int ci = min(max(bi - 1 + (t >> 4), 0), 15);
    int cj = t & 15;
    den_s[t] = den[(b << 8) + ci * 16 + cj] + 1e-16f;
  }
  __syncthreads();
  for (int o = t; o < 768; o += 256) {
    int lr = o >> 4, f4i = o & 15;
    int ci = min(max(bi - 1 + (lr >> 4), 0), 15);
    int cj = lr & 15;
    float4 v = *(const float4*)(num + (((b << 8) + ci * 16 + cj) << 6) + f4i * 4);
    float inv = 1.f / den_s[lr];
    v.x *= inv; v.y *= inv; v.z *= inv; v.w *= inv;
    *(float4*)&cent_s[lr * 68 + f4i * 4] = v;
  }
  __syncthreads();
  for (int o = t; o < 384; o += 256) {
    int lr = o >> 3, pt = o & 7;
    float s = 0.f;
#pragma unroll
    for (int m = 0; m < 8; m++) { float v = cent_s[lr * 68 + pt * 8 + m]; s += v * v; }
    c2p[o] = s;
  }
  __syncthreads();
  if (t < 48) {
    float s = 0.f;
#pragma unroll
    for (int m = 0; m < 8; m++) s += c2p[t * 8 + m];
    c2_s[t] = s;
  }
  __syncthreads();

  int j = t, bj = j >> 4;
  int cidx[9];
  float c2k[9];
  int vbits = 0;
#pragma unroll
  for (int k = 0; k < 9; k++) {
    int di = k / 3 - 1, dj = k % 3 - 1;
    int ciu = bi + di, cju = bj + dj;
    if ((unsigned)ciu < 16u && (unsigned)cju < 16u) vbits |= 1 << k;
    int lidx = (di + 1) * 16 + min(max(cju, 0), 15);
    cidx[k] = lidx * 68;
    c2k[k] = c2_s[lidx];
  }
  const float* base = x + ((long)(b * 64) << 16) + (i << 8) + j;
  float acc[9];
#pragma unroll
  for (int k = 0; k < 9; k++) acc[k] = 0.f;
#pragma unroll 8
  for (int c = 0; c < 64; c++) {
    float xv = base[(long)c << 16];
#pragma unroll
    for (int k = 0; k < 9; k++) acc[k] = fmaf(xv, cent_s[cidx[k] + c], acc[k]);
  }
  float mx = -1e30f;
#pragma unroll
  for (int k = 0; k < 9; k++) {
    float l = 2.f * acc[k] - c2k[k];
    acc[k] = ((vbits >> k) & 1) ? l : -1e30f;
    mx = fmaxf(mx, acc[k]);
  }
  float sum = 0.f;
#pragma unroll
  for (int k = 0; k < 9; k++) {
    acc[k] = __expf(acc[k] - mx);
    sum += acc[k];
  }
  float rs = 1.f / sum;
#pragma unroll
  for (int k = 0; k < 9; k++) aff_t[k * 260 + j] = acc[k] * rs;
  __syncthreads();

  // strip stores: work item o in [0,576): si_idx = o/192, sj = (o%192)/12,
  // u4 = o%12 -> j4 = 4*sj - 4 + u4. plane s = (bi-1+si_idx)*16 + sj,
  // k = si_idx*3 + (sj - (j4>>2)) + 1. 64B-aligned 16B stores, value from LDS.
  long obase = ((long)(b << 8)) << 14;
#pragma unroll
  for (int step = 0; step < 3; step++) {
    int o = step * 256 + t;
    if (o >= 576) break;
    int si_idx = o / 192;
    int rem = o - si_idx * 192;
    int sj = rem / 12;
    int u4 = rem - sj * 12;
    int si = bi - 1 + si_idx;
    int j4 = 4 * sj - 4 + u4;
    if ((unsigned)si < 16u && (unsigned)j4 < 64u) {
      int k = si_idx * 3 + (sj - (j4 >> 2)) + 1;
      f32x4 v = *(const f32x4*)&aff_t[k * 260 + (j4 << 2)];
      int s = si * 16 + sj;
      out4[obase + ((long)s << 14) + (i << 6) + j4] = v;
    }
  }
}

extern "C" void kernel_launch(void* const* d_in, const int* in_sizes, int n_in,
                              void* d_out, int out_size, void* d_ws, size_t ws_size,
                              hipStream_t stream) {
  const float* x = (const float*)d_in[0];
  float* out = (float*)d_out;
  float* ws = (float*)d_ws;

  float* num   = ws;
  float* den   = ws + 65536;
  float* cent0 = ws + 66560;

  k_init<<<1024, 256, 0, stream>>>(x, cent0, (float4*)ws);
  k_statz<<<2048, 256, 0, stream>>>(x, cent0, num, den, (f32x4*)out);
  k_strip<<<1024, 256, 0, stream>>>(x, num, den, (f32x4*)out);
}